// Round 9
// baseline (245.051 us; speedup 1.0000x reference)
//
#include <hip/hip_runtime.h>
#include <math.h>

// SoftMSM loss on MI355X — round 8.
// E-space linear DP (exact exp-space softmin3, verified absmax 0.0 R4/R6/R7)
// on a single-wave skewed pipeline with DPP boundary exchange.
//
// KEY INSIGHT (fit of rounds 3-7): per-step cost ~= #DS_ops * ~120cyc + issue.
// ds_bpermute (__shfl_up) and per-step ds_read prefetches were serialized on
// the critical loop; the barrier variants additionally drained lgkmcnt every
// step. Fix: wave_shr:1 DPP (ctrl 0x138, gfx9-lineage VALU cross-lane, ~2cyc)
// replaces all shuffles; row data packed float4, prefetched 1 step ahead.
//
// Recursion (c=1, gamma=1), F = e^{i+j} * exp(-cost):
//   F[i,j] = F[i-1,j-1]*A + F[i-1,j]*B + F[i,j-1]*C
//   A = e^{2-m2}; B = (dx*(x-y)>0 ? ex2+Em : 1); C = (dy*(x-y)<0 ? edy2+Em : 1)
//   cost = 1022 - log(F[511,511])
// Lane j owns cols [8j, 8j+8); at step t processes row-pair p = t - j
// (rows 2p, 2p+1). Carries dc0/dc1/dc2 = lastcol(2p-1, 2p, 2p+1), scale
// 2^kacc, rebased to max(kacc, k_in) per step (shifts <= 0, overflow-proof).

#define TT 512
#define BATCH 64
#define G 8                      // cols per lane
#define NP (TT / 2)              // 256 row-pairs
#define STEPS (NP + 63)          // 319

#define C1F 1.2011224087864498f  // sqrt(log2 e)
#define C2F 2.8853900817779268f  // 2*log2 e
#define K2F 0.13533528323661270f // e^-2
#define LN2F 0.69314718055994531f

#if __has_builtin(__builtin_amdgcn_exp2f)
#define EXP2F(x) __builtin_amdgcn_exp2f(x)
#else
#define EXP2F(x) __expf((x) * LN2F)
#endif

// lane i gets lane i-1's src; lane 0 gets `old`  (wave_shr:1 = 0x138)
__device__ __forceinline__ float dpp_shr1_f(float src, float old) {
  return __int_as_float(__builtin_amdgcn_update_dpp(
      __float_as_int(old), __float_as_int(src), 0x138, 0xF, 0xF, false));
}
__device__ __forceinline__ int dpp_shr1_i(int src, int old) {
  return __builtin_amdgcn_update_dpp(old, src, 0x138, 0xF, 0xF, false);
}

__global__ __launch_bounds__(64, 1) void msm_kernel(const float* __restrict__ x,
                                                    const float* __restrict__ y,
                                                    float* __restrict__ ws) {
  const int b = blockIdx.x;
  const int j = threadIdx.x;         // 0..63

  __shared__ float4 RD[TT];          // per-row: {xc = x*C1, dx, exp(-dx^2), 0}

  // ---- setup: x-derived row data ----
  {
    const float4* xv = (const float4*)(x + b * TT);
    float4 a0 = xv[j * 2], a1 = xv[j * 2 + 1];
    float rx[G] = {a0.x, a0.y, a0.z, a0.w, a1.x, a1.y, a1.z, a1.w};
    float prev = (j > 0) ? x[b * TT + 8 * j - 1] : 0.0f;
#pragma unroll
    for (int k = 0; k < G; ++k) {
      float dx = rx[k] - prev;       // row 0's dx unused (up input is 0)
      prev = rx[k];
      RD[8 * j + k] = make_float4(rx[k] * C1F, dx, __expf(-dx * dx), 0.0f);
    }
  }
  // ---- setup: y-derived column registers ----
  float yc[G], dyS[G], edy2[G];
  {
    const float4* yv = (const float4*)(y + b * TT);
    float4 a0 = yv[j * 2], a1 = yv[j * 2 + 1];
    float ry[G] = {a0.x, a0.y, a0.z, a0.w, a1.x, a1.y, a1.z, a1.w};
    float prev = (j > 0) ? y[b * TT + 8 * j - 1] : 0.0f;
#pragma unroll
    for (int k = 0; k < G; ++k) {
      float dy = ry[k] - prev;       // col 0's dy unused (left input is 0)
      prev = ry[k];
      yc[k] = ry[k] * C1F;
      dyS[k] = dy;
      edy2[k] = __expf(-dy * dy);
    }
  }
  __syncthreads();

  float Ep[G];                       // F[2p-1, owned cols], lane scale 2^kacc
#pragma unroll
  for (int k = 0; k < G; ++k) Ep[k] = 0.0f;
  float dc0 = 0.0f, dc1 = 0.0f, dc2 = 0.0f;  // lastcol(2p-1, 2p, 2p+1)
  int kacc = 0;

  // prefetch row-pair for t=0 (valid only for lane 0; others clamped)
  float4 rA = RD[0], rB = RD[1];

  for (int t = 0; t < STEPS; ++t) {
    // boundary exchange via DPP (VALU pipe, no LDS) — all lanes, uniform
    float r0 = dpp_shr1_f(dc0, 0.0f);
    float r1 = dpp_shr1_f(dc1, 0.0f);
    float r2 = dpp_shr1_f(dc2, 0.0f);
    int k_in = dpp_shr1_i(kacc, kacc);       // lane 0: own kacc
    if (t == 0 && j == 0) r0 = K2F;          // global seed F[-1,-1] = e^{-2}

    const int p = t - j;
    // rotate prefetched row data; prefetch next pair (off critical path)
    const float4 cA = rA, cB = rB;
    {
      int pn = t + 1 - j;
      pn = (pn < 0) ? 0 : ((pn > NP - 1) ? NP - 1 : pn);
      rA = RD[2 * pn];
      rB = RD[2 * pn + 1];
    }

    if (p >= 0 && p < NP) {
      if (p == 0) kacc = k_in;               // pipeline entry: adopt scale
      const int knew = (k_in > kacc) ? k_in : kacc;
      const float mMe = ldexpf(1.0f, kacc - knew);  // <= 1
      const float mIn = ldexpf(1.0f, k_in - knew);  // <= 1
      kacc = knew;
      const float dv0 = r0 * mIn, dv1 = r1 * mIn, dv2 = r2 * mIn;
      const float nd0 = dc2 * mMe;           // lastcol(2p-1) for next send
      float u[G];
#pragma unroll
      for (int k = 0; k < G; ++k) u[k] = Ep[k] * mMe;

      // one cell: out = l*Cw + d*A + u*B
#define CELL(xcv, dxv, exv, kk, uu, d, l, out)                         \
      {                                                                \
        float s1 = (xcv) - yc[kk];                                     \
        float A = EXP2F(__fmaf_rn(s1, -s1, C2F));                      \
        float Em = A * K2F;                                            \
        float B = ((dxv) * s1 > 0.0f) ? ((exv) + Em) : 1.0f;           \
        float Cw = (dyS[kk] * s1 < 0.0f) ? (edy2[kk] + Em) : 1.0f;     \
        out = __fmaf_rn(l, Cw, __fmaf_rn(d, A, (uu) * B));             \
      }

      float T0[G], T1[G];
      // row 2p:   u = u[k], d = (k?u[k-1]:dv0), l = (k?T0[k-1]:dv1)
      CELL(cA.x, cA.y, cA.z, 0, u[0], dv0, dv1, T0[0]);
#pragma unroll
      for (int k = 1; k < G; ++k)
        CELL(cA.x, cA.y, cA.z, k, u[k], u[k - 1], T0[k - 1], T0[k]);
      // row 2p+1: u = T0[k], d = (k?T0[k-1]:dv1), l = (k?T1[k-1]:dv2)
      CELL(cB.x, cB.y, cB.z, 0, T0[0], dv1, dv2, T1[0]);
#pragma unroll
      for (int k = 1; k < G; ++k)
        CELL(cB.x, cB.y, cB.z, k, T0[k], T0[k - 1], T1[k - 1], T1[k]);
#undef CELL

      dc0 = nd0;
      dc1 = T0[G - 1];
      // normalize carried state into [0.5, 1)
      float vmax = fmaxf(fmaxf(fmaxf(T1[0], T1[1]), fmaxf(T1[2], T1[3])),
                         fmaxf(fmaxf(T1[4], T1[5]), fmaxf(T1[6], T1[7])));
      vmax = fmaxf(vmax, fmaxf(dc0, dc1));
      unsigned ue = (__float_as_uint(vmax) >> 23) & 0xFFu;
      int e = (int)ue - 126;
      float sc = ldexpf(1.0f, -e);
#pragma unroll
      for (int k = 0; k < G; ++k) Ep[k] = T1[k] * sc;
      dc0 *= sc;
      dc1 *= sc;
      dc2 = Ep[G - 1];
      kacc += e;
    }
  }

  if (j == 63) {
    // cost = 1022 - log(F_true)
    ws[b] = 1022.0f - (__logf(Ep[G - 1]) + (float)kacc * LN2F);
  }
}

__global__ __launch_bounds__(64) void reduce_kernel(const float* __restrict__ ws,
                                                    float* __restrict__ out) {
  float v = ws[threadIdx.x];
#pragma unroll
  for (int off = 32; off > 0; off >>= 1) v += __shfl_down(v, off);
  if (threadIdx.x == 0) out[0] = v * (1.0f / BATCH);
}

extern "C" void kernel_launch(void* const* d_in, const int* in_sizes, int n_in,
                              void* d_out, int out_size, void* d_ws, size_t ws_size,
                              hipStream_t stream) {
  const float* x = (const float*)d_in[0];
  const float* y = (const float*)d_in[1];
  float* ws = (float*)d_ws;
  float* out = (float*)d_out;
  msm_kernel<<<BATCH, 64, 0, stream>>>(x, y, ws);
  reduce_kernel<<<1, 64, 0, stream>>>(ws, out);
}

// Round 10
// 219.060 us; speedup vs baseline: 1.1187x; 1.1187x over previous
//
#include <hip/hip_runtime.h>
#include <math.h>

// SoftMSM loss on MI355X — round 9.
// R7 skeleton (2 barrier-synced waves/problem, 383 steps, verified absmax 0.0)
// + R8's DPP boundary exchange (verified) + EXPLICIT weight/chain phase split.
//
// Cross-round invariant: ~90 cyc/cell everywhere == v_exp_f32 latency inlined
// on the serial FMA chain (compiler never hoists it: R8 VGPR_Count=44).
// Fix: compute all 8 cells' (A,B,C) into arrays FIRST (8 independent exps
// pipeline at issue rate), then run the pure-FMA chain (path ~60 cyc).
//
// Recursion (c=1, gamma=1), F = e^{i+j} * exp(-cost):
//   F[i,j] = F[i-1,j-1]*A + F[i-1,j]*B + F[i,j-1]*C
//   A = e^{2-m2}; B = (dx*(x-y)>0 ? ex2+Em : 1); C = (dy*(x-y)<0 ? edy2+Em : 1)
//   cost = 1022 - log(F[511,511])
// Lane L (0..127) owns cols [4L,4L+4); step t processes row-pair p = t - L.
// Intra-wave neighbor via DPP wave_shr:1; wave0->wave1 seam via parity
// double-buffered LDS slot + one __syncthreads/step. Per-lane scale 2^kacc,
// rebase to max(kacc,k_in) (shifts <= 0, overflow-proof), normalize per step.

#define TT 512
#define BATCH 64
#define G 4                      // cols per lane
#define LANES 128
#define NP (TT / 2)              // 256 row-pairs
#define STEPS (NP + LANES - 1)   // 383

#define C1F 1.2011224087864498f  // sqrt(log2 e)
#define C2F 2.8853900817779268f  // 2*log2 e
#define K2F 0.13533528323661270f // e^-2
#define LN2F 0.69314718055994531f

#if __has_builtin(__builtin_amdgcn_exp2f)
#define EXP2F(x) __builtin_amdgcn_exp2f(x)
#else
#define EXP2F(x) __expf((x) * LN2F)
#endif

// lane i gets lane i-1's src within its wave; lane 0 of the wave gets `old`
__device__ __forceinline__ float dpp_shr1_f(float src, float old) {
  return __int_as_float(__builtin_amdgcn_update_dpp(
      __float_as_int(old), __float_as_int(src), 0x138, 0xF, 0xF, false));
}
__device__ __forceinline__ int dpp_shr1_i(int src, int old) {
  return __builtin_amdgcn_update_dpp(old, src, 0x138, 0xF, 0xF, false);
}

__global__ __launch_bounds__(128, 1) void msm_kernel(const float* __restrict__ x,
                                                     const float* __restrict__ y,
                                                     float* __restrict__ ws) {
  const int b = blockIdx.x;
  const int tid = threadIdx.x;       // 0..127

  __shared__ float2 XC2[NP];         // {xc(2p), xc(2p+1)}, xc = x * C1
  __shared__ float2 DX2[NP];
  __shared__ float2 EX2[NP];
  __shared__ float4 slotV[2];        // seam values {r0, r1, r2, -}
  __shared__ int    slotK[2];        // seam scale

  // ---- setup (verbatim R7) ----
  {
    float4 xq = ((const float4*)(x + b * TT))[tid];
    float rx[4] = {xq.x, xq.y, xq.z, xq.w};
    float prev = (tid > 0) ? x[b * TT + 4 * tid - 1] : 0.0f;
    float cc[4], dd[4], ee[4];
#pragma unroll
    for (int k = 0; k < 4; ++k) {
      float dx = rx[k] - prev;       // row 0's dx unused (up input is 0)
      prev = rx[k];
      cc[k] = rx[k] * C1F;
      dd[k] = dx;
      ee[k] = __expf(-dx * dx);
    }
    XC2[2 * tid]     = make_float2(cc[0], cc[1]);
    XC2[2 * tid + 1] = make_float2(cc[2], cc[3]);
    DX2[2 * tid]     = make_float2(dd[0], dd[1]);
    DX2[2 * tid + 1] = make_float2(dd[2], dd[3]);
    EX2[2 * tid]     = make_float2(ee[0], ee[1]);
    EX2[2 * tid + 1] = make_float2(ee[2], ee[3]);
  }
  float yc[G], dyS[G], edy2[G];
  {
    float4 yq = ((const float4*)(y + b * TT))[tid];
    float ry[G] = {yq.x, yq.y, yq.z, yq.w};
    float prev = (tid > 0) ? y[b * TT + 4 * tid - 1] : 0.0f;
#pragma unroll
    for (int k = 0; k < G; ++k) {
      float dy = ry[k] - prev;       // col 0's dy unused (left input is 0)
      prev = ry[k];
      yc[k] = ry[k] * C1F;
      dyS[k] = dy;
      edy2[k] = __expf(-dy * dy);
    }
  }
  if (tid < 2) {
    slotV[tid] = make_float4(0.0f, 0.0f, 0.0f, 0.0f);
    slotK[tid] = 0;
  }
  __syncthreads();

  float Ep[G] = {0.0f, 0.0f, 0.0f, 0.0f};   // F[2p-1, owned cols]
  float dc0 = 0.0f, dc1 = 0.0f, dc2 = 0.0f; // lastcol(2p-1, 2p, 2p+1)
  int kacc = 0;

  float2 nxc = XC2[0], ndx = DX2[0], nex = EX2[0];

  for (int t = 0; t < STEPS; ++t) {
    // intra-wave boundary exchange via DPP (VALU pipe, no LDS)
    float r0 = dpp_shr1_f(dc0, 0.0f);
    float r1 = dpp_shr1_f(dc1, 0.0f);
    float r2 = dpp_shr1_f(dc2, 0.0f);
    int k_in = dpp_shr1_i(kacc, kacc);     // wave-lane 0 keeps own kacc
    __syncthreads();                       // publishes slot written at t-1
    const int p = t - tid;
    if (tid == 64) {                       // seam: wave0 lane63 -> wave1 lane0
      float4 s = slotV[(t + 1) & 1];
      r0 = s.x; r1 = s.y; r2 = s.z;
      k_in = slotK[(t + 1) & 1];
    }
    if (tid == 0 && p == 0) r0 = K2F;      // global seed F[-1,-1] = e^{-2}

    const float2 cxc = nxc, cdx = ndx, cex = nex;
    {
      int pn = t + 1 - tid;
      pn = (pn < 0) ? 0 : ((pn > NP - 1) ? NP - 1 : pn);
      nxc = XC2[pn]; ndx = DX2[pn]; nex = EX2[pn];
    }

    if (p >= 0 && p < NP) {
      if (p == 0) kacc = k_in;             // pipeline entry: adopt scale
      const int knew = (k_in > kacc) ? k_in : kacc;
      const float mMe = ldexpf(1.0f, kacc - knew);  // <= 1
      const float mIn = ldexpf(1.0f, k_in - knew);  // <= 1
      kacc = knew;
      const float dv0 = r0 * mIn, dv1 = r1 * mIn, dv2 = r2 * mIn;
      const float nd0 = dc2 * mMe;
      float u[G];
#pragma unroll
      for (int k = 0; k < G; ++k) u[k] = Ep[k] * mMe;

      // ---- phase 1: ALL weights (8 independent exps, no chain deps) ----
      float Aa[G], Ba[G], Ca[G], Ab[G], Bb[G], Cb[G];
#pragma unroll
      for (int k = 0; k < G; ++k) {
        float s1a = cxc.x - yc[k];
        float s1b = cxc.y - yc[k];
        float A_a = EXP2F(__fmaf_rn(s1a, -s1a, C2F));
        float A_b = EXP2F(__fmaf_rn(s1b, -s1b, C2F));
        float Ema = A_a * K2F;
        float Emb = A_b * K2F;
        Aa[k] = A_a;  Ab[k] = A_b;
        Ba[k] = (cdx.x * s1a > 0.0f) ? (cex.x + Ema) : 1.0f;
        Bb[k] = (cdx.y * s1b > 0.0f) ? (cex.y + Emb) : 1.0f;
        Ca[k] = (dyS[k] * s1a < 0.0f) ? (edy2[k] + Ema) : 1.0f;
        Cb[k] = (dyS[k] * s1b < 0.0f) ? (edy2[k] + Emb) : 1.0f;
      }
      // ---- phase 2: pure-FMA chains ----
      float pa[G], T0[G];
      pa[0] = __fmaf_rn(dv0, Aa[0], u[0] * Ba[0]);
#pragma unroll
      for (int k = 1; k < G; ++k) pa[k] = __fmaf_rn(u[k - 1], Aa[k], u[k] * Ba[k]);
      T0[0] = __fmaf_rn(dv1, Ca[0], pa[0]);
#pragma unroll
      for (int k = 1; k < G; ++k) T0[k] = __fmaf_rn(T0[k - 1], Ca[k], pa[k]);

      float pb[G], T1[G];
      pb[0] = __fmaf_rn(dv1, Ab[0], T0[0] * Bb[0]);
#pragma unroll
      for (int k = 1; k < G; ++k) pb[k] = __fmaf_rn(T0[k - 1], Ab[k], T0[k] * Bb[k]);
      T1[0] = __fmaf_rn(dv2, Cb[0], pb[0]);
#pragma unroll
      for (int k = 1; k < G; ++k) T1[k] = __fmaf_rn(T1[k - 1], Cb[k], pb[k]);

      dc0 = nd0;
      dc1 = T0[G - 1];
      // normalize carried state into [0.5, 1)
      float vmax = fmaxf(fmaxf(fmaxf(T1[0], T1[1]), fmaxf(T1[2], T1[3])),
                         fmaxf(dc0, dc1));
      unsigned ue = (__float_as_uint(vmax) >> 23) & 0xFFu;
      int e = (int)ue - 126;
      float sc = ldexpf(1.0f, -e);
#pragma unroll
      for (int k = 0; k < G; ++k) Ep[k] = T1[k] * sc;
      dc0 *= sc;
      dc1 *= sc;
      dc2 = Ep[G - 1];
      kacc += e;

      if (tid == 63) {                     // producer: publish seam for t+1
        slotV[t & 1] = make_float4(dc0, dc1, dc2, 0.0f);
        slotK[t & 1] = kacc;
      }
    }
  }

  if (tid == 127) {
    ws[b] = 1022.0f - (__logf(Ep[G - 1]) + (float)kacc * LN2F);
  }
}

__global__ __launch_bounds__(64) void reduce_kernel(const float* __restrict__ ws,
                                                    float* __restrict__ out) {
  float v = ws[threadIdx.x];
#pragma unroll
  for (int off = 32; off > 0; off >>= 1) v += __shfl_down(v, off);
  if (threadIdx.x == 0) out[0] = v * (1.0f / BATCH);
}

extern "C" void kernel_launch(void* const* d_in, const int* in_sizes, int n_in,
                              void* d_out, int out_size, void* d_ws, size_t ws_size,
                              hipStream_t stream) {
  const float* x = (const float*)d_in[0];
  const float* y = (const float*)d_in[1];
  float* ws = (float*)d_ws;
  float* out = (float*)d_out;
  msm_kernel<<<BATCH, LANES, 0, stream>>>(x, y, ws);
  reduce_kernel<<<1, 64, 0, stream>>>(ws, out);
}